// Round 6
// baseline (186.174 us; speedup 1.0000x reference)
//
#include <hip/hip_runtime.h>
#include <hip/hip_bf16.h>

// CAM: per batch b (B=16):  a = x[b] viewed as [N=4096, C=256]
//   aTa  = a^T a            [C, C]
//   attn = softmax(aTa, -1)
//   y    = a · attn         [N, C]
//   out  = gamma * y + x
// Storage: fp32 (values bf16-quantized by harness). Internal: bf16 MFMA, fp32 accum.
//
// R5->R6: budget model (fits R0-R5): dur_us = ~82us harness poison-fills
// (uncontrollable) + gemm1 ~33 + softmax ~9 + gemm2 41. gemm2 counters
// (MfmaUtil 7%, HBM 44%, Occ 28%) = phase serialization: one residency
// round, lockstep stage->barrier->compute->store, dead head+tail.
// New gemm2: NO LDS, NO barriers — pure streaming K-loop. A-fragments read
// direct from global (32B fp32 per lane per k-step, cvt in VALU; rows are
// L2-hot after first touch, so the 4x per-block A re-read is L2 traffic,
// HBM unchanged at ~130MB). B direct from global as R5 (16B/lane; lanes
// sharing lm across lk quadrants fill whole 64B lines -> fully coalesced).
// Compiler free to software-pipeline; launch_bounds(256,2) for VGPR room.
// gemm1 + softmax byte-identical to R5 (single-subsystem attribution).
// NOTE gamma==0 => harness only verifies the x-passthrough; gemm1/softmax/
// y-path correctness rests on the hand-verified layouts (unchanged here).

#define BB 16
#define NN 4096   // H*W
#define CC 256
#define SPLITK 8
#define KCHUNK (NN / SPLITK)   // 512

typedef __attribute__((ext_vector_type(4))) short short4v;
typedef __attribute__((ext_vector_type(8))) short short8v;
typedef __attribute__((ext_vector_type(4))) float floatx4;

__device__ __forceinline__ unsigned short f2bf(float f) {
    unsigned int u = __float_as_uint(f);
    u += 0x7fffu + ((u >> 16) & 1u);   // RNE (exact for already-bf16-grid values)
    return (unsigned short)(u >> 16);
}
__device__ __forceinline__ short4v cvt4(floatx4 v) {
    short4v r;
    r[0] = (short)f2bf(v[0]); r[1] = (short)f2bf(v[1]);
    r[2] = (short)f2bf(v[2]); r[3] = (short)f2bf(v[3]);
    return r;
}

// ---------------- K1: part[split][b] = partial a^T a (fused transpose) ----
// grid (SPLITK, BB, 2) = 256 blocks, 512 threads (8 waves), 2 waves/SIMD.
// (Exact R2/R5 version — known-good, ~33us by budget model.)
__global__ __launch_bounds__(512, 2) void k_gemm1(const float* __restrict__ x,
                                                  float* __restrict__ part) {
    __shared__ unsigned short P[256 * 72];   // [c][64 slots + pad], 36.9 KB
    const int split = blockIdx.x;
    const int b     = blockIdx.y;
    const int half  = blockIdx.z;
    const int t  = threadIdx.x;
    const int w  = t >> 6, l = t & 63;
    const int lk = (l >> 4) * 8;
    const int lm = l & 15;
    const int i0 = half * 128;
    const int wr = (w >> 2) * 64;            // wave tile 64 x 64
    const int wc = (w & 3) * 64;
    const unsigned swz = (unsigned)(l & 7) << 3;   // == ((c>>2)&7)<<3 for c=4l+j

    const float* xb = x + ((size_t)b * NN + (size_t)split * KCHUNK) * CC + 4 * l;

    floatx4 pf[8];
    #pragma unroll
    for (int p = 0; p < 8; ++p)
        pf[p] = *(const floatx4*)(xb + (size_t)(w + 8 * p) * CC);   // n = w + 8p

    floatx4 acc[4][4] = {};

    for (int k0 = 0; k0 < KCHUNK; k0 += 64) {
        // bf16 convert + in-register 8x4 -> 4x8 transpose
        short4v s[8];
        #pragma unroll
        for (int p = 0; p < 8; ++p) s[p] = cvt4(pf[p]);
        #pragma unroll
        for (int j = 0; j < 4; ++j) {
            short8v o;
            #pragma unroll
            for (int e = 0; e < 8; ++e) o[e] = s[e][j];   // n = w + 8e
            const unsigned c = (unsigned)(4 * l + j);
            *(short8v*)&P[c * 72 + (((unsigned)(8 * w)) ^ swz)] = o;
        }
        __syncthreads();
        // prefetch next 64-n chunk
        if (k0 + 64 < KCHUNK) {
            const float* xn = xb + (size_t)(k0 + 64) * CC;
            #pragma unroll
            for (int p = 0; p < 8; ++p)
                pf[p] = *(const floatx4*)(xn + (size_t)(w + 8 * p) * CC);
        }
        #pragma unroll
        for (int ks = 0; ks < 64; ks += 32) {
            short8v af[4], bf[4];
            #pragma unroll
            for (int mt = 0; mt < 4; ++mt) {
                const unsigned row = (unsigned)(i0 + wr + mt * 16 + lm);
                af[mt] = *(const short8v*)&P[row * 72 + (((unsigned)(ks + lk)) ^ (((row >> 2) & 7u) << 3))];
            }
            #pragma unroll
            for (int nt = 0; nt < 4; ++nt) {
                const unsigned row = (unsigned)(wc + nt * 16 + lm);
                bf[nt] = *(const short8v*)&P[row * 72 + (((unsigned)(ks + lk)) ^ (((row >> 2) & 7u) << 3))];
            }
            #pragma unroll
            for (int mt = 0; mt < 4; ++mt)
                #pragma unroll
                for (int nt = 0; nt < 4; ++nt)
                    acc[mt][nt] = __builtin_amdgcn_mfma_f32_16x16x32_bf16(af[mt], bf[nt], acc[mt][nt], 0, 0, 0);
        }
        __syncthreads();
    }
    const int orow = (l >> 4) * 4;    // C/D: row=(lane>>4)*4+r, col=lane&15
    float* pout = part + (size_t)(split * BB + b) * CC * CC;
    #pragma unroll
    for (int mt = 0; mt < 4; ++mt)
        #pragma unroll
        for (int nt = 0; nt < 4; ++nt)
            #pragma unroll
            for (int r = 0; r < 4; ++r) {
                int i = i0 + wr + mt * 16 + orow + r;
                int j = wc + nt * 16 + lm;
                pout[(size_t)i * CC + j] = acc[mt][nt][r];
            }
}

// ---------------- K2: attn_T[b][j][i] = softmax over summed partials ----
__global__ __launch_bounds__(256) void k_softmax(const float* __restrict__ part,
                                                 unsigned short* __restrict__ attnT) {
    const int w = threadIdx.x >> 6;
    const int l = threadIdx.x & 63;
    const int row = blockIdx.x * 4 + w;   // 0..B*C-1
    const int b = row >> 8;
    const int i = row & 255;
    float v0 = 0.f, v1 = 0.f, v2 = 0.f, v3 = 0.f;
    #pragma unroll
    for (int s = 0; s < SPLITK; ++s) {
        const float* p = part + ((size_t)(s * BB + b) * CC + i) * CC;
        v0 += p[l]; v1 += p[l + 64]; v2 += p[l + 128]; v3 += p[l + 192];
    }
    float m = fmaxf(fmaxf(v0, v1), fmaxf(v2, v3));
    for (int off = 32; off >= 1; off >>= 1) m = fmaxf(m, __shfl_xor(m, off, 64));
    v0 = __expf(v0 - m); v1 = __expf(v1 - m); v2 = __expf(v2 - m); v3 = __expf(v3 - m);
    float s = v0 + v1 + v2 + v3;
    for (int off = 32; off >= 1; off >>= 1) s += __shfl_xor(s, off, 64);
    float rs = 1.0f / s;
    unsigned short* o = attnT + (size_t)b * CC * CC + i;   // attnT[b][j][i]
    o[(size_t)(l +   0) * CC] = f2bf(v0 * rs);
    o[(size_t)(l +  64) * CC] = f2bf(v1 * rs);
    o[(size_t)(l + 128) * CC] = f2bf(v2 * rs);
    o[(size_t)(l + 192) * CC] = f2bf(v3 * rs);
}

// ---------------- K3: out = gamma * (a · attn) + x ----------------------
// LDS-free, barrier-free streaming GEMM. grid (64, BB) = 1024 blocks, 4 waves.
// Per k-step: A direct from global (fp32->bf16 cvt in VALU, rows L2-hot),
// B direct from global (L2-resident attnT[b]); 16 MFMA. No phases at all.
__global__ __launch_bounds__(256, 2) void k_gemm2(const float* __restrict__ x,
                                                  const unsigned short* __restrict__ attnT,
                                                  const float* __restrict__ gamma,
                                                  float* __restrict__ out) {
    const int n0 = blockIdx.x * 64;
    const int b  = blockIdx.y;
    const int t  = threadIdx.x;
    const int w  = t >> 6, l = t & 63;
    const int lk = (l >> 4) * 8, lm = l & 15;

    const float*          Ab = x + ((size_t)b * NN + n0) * CC;
    const unsigned short* Bb = attnT + (size_t)b * CC * CC;

    floatx4 acc[4][4] = {};
    #pragma unroll
    for (int k0 = 0; k0 < CC; k0 += 32) {
        short8v af[4], bf[4];
        #pragma unroll
        for (int mt = 0; mt < 4; ++mt) {
            const float* rp = Ab + (size_t)(mt * 16 + lm) * CC + k0 + lk;
            floatx4 lo = *(const floatx4*)rp;
            floatx4 hi = *(const floatx4*)(rp + 4);
            short4v sl = cvt4(lo), sh = cvt4(hi);
            af[mt][0] = sl[0]; af[mt][1] = sl[1]; af[mt][2] = sl[2]; af[mt][3] = sl[3];
            af[mt][4] = sh[0]; af[mt][5] = sh[1]; af[mt][6] = sh[2]; af[mt][7] = sh[3];
        }
        #pragma unroll
        for (int nt = 0; nt < 4; ++nt)
            bf[nt] = *(const short8v*)(Bb + (size_t)(w * 64 + nt * 16 + lm) * CC + k0 + lk);
        #pragma unroll
        for (int mt = 0; mt < 4; ++mt)
            #pragma unroll
            for (int nt = 0; nt < 4; ++nt)
                acc[mt][nt] = __builtin_amdgcn_mfma_f32_16x16x32_bf16(af[mt], bf[nt], acc[mt][nt], 0, 0, 0);
    }

    // ---- epilogue: 4x4 shfl-xor transpose -> float4 (unchanged from R5) ----
    const float g = gamma[0];
    const int orow = (l >> 4) * 4;
    #pragma unroll
    for (int mt = 0; mt < 4; ++mt)
        #pragma unroll
        for (int nt = 0; nt < 4; ++nt) {
            float v0 = acc[mt][nt][0], v1 = acc[mt][nt][1];
            float v2 = acc[mt][nt][2], v3 = acc[mt][nt][3];
            float tt;
            tt = __shfl_xor((lm & 1) ? v0 : v1, 1, 64); if (lm & 1) v0 = tt; else v1 = tt;
            tt = __shfl_xor((lm & 1) ? v2 : v3, 1, 64); if (lm & 1) v2 = tt; else v3 = tt;
            tt = __shfl_xor((lm & 2) ? v0 : v2, 2, 64); if (lm & 2) v0 = tt; else v2 = tt;
            tt = __shfl_xor((lm & 2) ? v1 : v3, 2, 64); if (lm & 2) v1 = tt; else v3 = tt;
            int nr = n0 + mt * 16 + orow + (lm & 3);
            int jc = w * 64 + nt * 16 + (lm & 12);
            size_t ro = ((size_t)b * NN + nr) * CC + jc;
            floatx4 xv = *(const floatx4*)(x + ro);
            floatx4 ov;
            ov[0] = g * v0 + xv[0]; ov[1] = g * v1 + xv[1];
            ov[2] = g * v2 + xv[2]; ov[3] = g * v3 + xv[3];
            *(floatx4*)(out + ro) = ov;
        }
}

extern "C" void kernel_launch(void* const* d_in, const int* in_sizes, int n_in,
                              void* d_out, int out_size, void* d_ws, size_t ws_size,
                              hipStream_t stream) {
    const float* x     = (const float*)d_in[0];
    const float* gamma = (const float*)d_in[1];
    float* out = (float*)d_out;

    char* ws = (char*)d_ws;
    float*          part  = (float*)ws;                                   // 8*16*256*256*4 = 32 MB
    unsigned short* attnT = (unsigned short*)(ws + (size_t)SPLITK * BB * CC * CC * 4);  // 2 MB

    k_gemm1  <<<dim3(SPLITK, BB, 2),  512, 0, stream>>>(x, part);
    k_softmax<<<dim3(BB * CC / 4),    256, 0, stream>>>(part, attnT);
    k_gemm2  <<<dim3(NN / 64, BB),    256, 0, stream>>>(x, attnT, gamma, out);
}

// Round 7
// 180.290 us; speedup vs baseline: 1.0326x; 1.0326x over previous
//
#include <hip/hip_runtime.h>
#include <hip/hip_bf16.h>

// CAM: per batch b (B=16):  a = x[b] viewed as [N=4096, C=256]
//   aTa  = a^T a            [C, C]
//   attn = softmax(aTa, -1)
//   y    = a · attn         [N, C]
//   out  = gamma * y + x
// Storage: fp32 (values bf16-quantized by harness). Internal: bf16 MFMA, fp32 accum.
//
// R6->R7: R6 (LDS-free gemm2) REGRESSED 41->65us: every MFMA operand became
// a global-latency dep (L2 ~200-400cy vs LDS ~120cy) and VGPR=68 left no
// room to pipeline the 12 loads/K-step -> serialized. REVERTED to R5's
// structure (LDS A-panel once + B direct from L2-hot global + shfl-transpose
// float4 epilogue). The R5 residual (41 vs 22us floor, Occ 27.7%) is
// ramp/phase/tail idleness at grid=exactly-4/CU with zero refill slack.
// Fix: BM 64->32. grid 2048 blocks, LDS 16.6KB, acc[2][4],
// launch_bounds(256,5) -> 5 blocks/CU + refill queue; halved staging phase,
// interleaved block phases, fine-grained tail.
// gemm1 + softmax byte-identical to R5/R2 (attribution).
// NOTE gamma==0 => harness only verifies the x-passthrough; y-path
// correctness rests on the hand-verified MFMA/swizzle layouts (unchanged).

#define BB 16
#define NN 4096   // H*W
#define CC 256
#define SPLITK 8
#define KCHUNK (NN / SPLITK)   // 512

typedef __attribute__((ext_vector_type(4))) short short4v;
typedef __attribute__((ext_vector_type(8))) short short8v;
typedef __attribute__((ext_vector_type(4))) float floatx4;

__device__ __forceinline__ unsigned short f2bf(float f) {
    unsigned int u = __float_as_uint(f);
    u += 0x7fffu + ((u >> 16) & 1u);   // RNE (exact for already-bf16-grid values)
    return (unsigned short)(u >> 16);
}
__device__ __forceinline__ short4v cvt4(floatx4 v) {
    short4v r;
    r[0] = (short)f2bf(v[0]); r[1] = (short)f2bf(v[1]);
    r[2] = (short)f2bf(v[2]); r[3] = (short)f2bf(v[3]);
    return r;
}

// ---------------- K1: part[split][b] = partial a^T a (fused transpose) ----
// grid (SPLITK, BB, 2) = 256 blocks, 512 threads (8 waves), 2 waves/SIMD.
// (Exact R2/R5 version — known-good, ~33us by budget model.)
__global__ __launch_bounds__(512, 2) void k_gemm1(const float* __restrict__ x,
                                                  float* __restrict__ part) {
    __shared__ unsigned short P[256 * 72];   // [c][64 slots + pad], 36.9 KB
    const int split = blockIdx.x;
    const int b     = blockIdx.y;
    const int half  = blockIdx.z;
    const int t  = threadIdx.x;
    const int w  = t >> 6, l = t & 63;
    const int lk = (l >> 4) * 8;
    const int lm = l & 15;
    const int i0 = half * 128;
    const int wr = (w >> 2) * 64;            // wave tile 64 x 64
    const int wc = (w & 3) * 64;
    const unsigned swz = (unsigned)(l & 7) << 3;   // == ((c>>2)&7)<<3 for c=4l+j

    const float* xb = x + ((size_t)b * NN + (size_t)split * KCHUNK) * CC + 4 * l;

    floatx4 pf[8];
    #pragma unroll
    for (int p = 0; p < 8; ++p)
        pf[p] = *(const floatx4*)(xb + (size_t)(w + 8 * p) * CC);   // n = w + 8p

    floatx4 acc[4][4] = {};

    for (int k0 = 0; k0 < KCHUNK; k0 += 64) {
        // bf16 convert + in-register 8x4 -> 4x8 transpose
        short4v s[8];
        #pragma unroll
        for (int p = 0; p < 8; ++p) s[p] = cvt4(pf[p]);
        #pragma unroll
        for (int j = 0; j < 4; ++j) {
            short8v o;
            #pragma unroll
            for (int e = 0; e < 8; ++e) o[e] = s[e][j];   // n = w + 8e
            const unsigned c = (unsigned)(4 * l + j);
            *(short8v*)&P[c * 72 + (((unsigned)(8 * w)) ^ swz)] = o;
        }
        __syncthreads();
        // prefetch next 64-n chunk
        if (k0 + 64 < KCHUNK) {
            const float* xn = xb + (size_t)(k0 + 64) * CC;
            #pragma unroll
            for (int p = 0; p < 8; ++p)
                pf[p] = *(const floatx4*)(xn + (size_t)(w + 8 * p) * CC);
        }
        #pragma unroll
        for (int ks = 0; ks < 64; ks += 32) {
            short8v af[4], bf[4];
            #pragma unroll
            for (int mt = 0; mt < 4; ++mt) {
                const unsigned row = (unsigned)(i0 + wr + mt * 16 + lm);
                af[mt] = *(const short8v*)&P[row * 72 + (((unsigned)(ks + lk)) ^ (((row >> 2) & 7u) << 3))];
            }
            #pragma unroll
            for (int nt = 0; nt < 4; ++nt) {
                const unsigned row = (unsigned)(wc + nt * 16 + lm);
                bf[nt] = *(const short8v*)&P[row * 72 + (((unsigned)(ks + lk)) ^ (((row >> 2) & 7u) << 3))];
            }
            #pragma unroll
            for (int mt = 0; mt < 4; ++mt)
                #pragma unroll
                for (int nt = 0; nt < 4; ++nt)
                    acc[mt][nt] = __builtin_amdgcn_mfma_f32_16x16x32_bf16(af[mt], bf[nt], acc[mt][nt], 0, 0, 0);
        }
        __syncthreads();
    }
    const int orow = (l >> 4) * 4;    // C/D: row=(lane>>4)*4+r, col=lane&15
    float* pout = part + (size_t)(split * BB + b) * CC * CC;
    #pragma unroll
    for (int mt = 0; mt < 4; ++mt)
        #pragma unroll
        for (int nt = 0; nt < 4; ++nt)
            #pragma unroll
            for (int r = 0; r < 4; ++r) {
                int i = i0 + wr + mt * 16 + orow + r;
                int j = wc + nt * 16 + lm;
                pout[(size_t)i * CC + j] = acc[mt][nt][r];
            }
}

// ---------------- K2: attn_T[b][j][i] = softmax over summed partials ----
__global__ __launch_bounds__(256) void k_softmax(const float* __restrict__ part,
                                                 unsigned short* __restrict__ attnT) {
    const int w = threadIdx.x >> 6;
    const int l = threadIdx.x & 63;
    const int row = blockIdx.x * 4 + w;   // 0..B*C-1
    const int b = row >> 8;
    const int i = row & 255;
    float v0 = 0.f, v1 = 0.f, v2 = 0.f, v3 = 0.f;
    #pragma unroll
    for (int s = 0; s < SPLITK; ++s) {
        const float* p = part + ((size_t)(s * BB + b) * CC + i) * CC;
        v0 += p[l]; v1 += p[l + 64]; v2 += p[l + 128]; v3 += p[l + 192];
    }
    float m = fmaxf(fmaxf(v0, v1), fmaxf(v2, v3));
    for (int off = 32; off >= 1; off >>= 1) m = fmaxf(m, __shfl_xor(m, off, 64));
    v0 = __expf(v0 - m); v1 = __expf(v1 - m); v2 = __expf(v2 - m); v3 = __expf(v3 - m);
    float s = v0 + v1 + v2 + v3;
    for (int off = 32; off >= 1; off >>= 1) s += __shfl_xor(s, off, 64);
    float rs = 1.0f / s;
    unsigned short* o = attnT + (size_t)b * CC * CC + i;   // attnT[b][j][i]
    o[(size_t)(l +   0) * CC] = f2bf(v0 * rs);
    o[(size_t)(l +  64) * CC] = f2bf(v1 * rs);
    o[(size_t)(l + 128) * CC] = f2bf(v2 * rs);
    o[(size_t)(l + 192) * CC] = f2bf(v3 * rs);
}

// ---------------- K3: out = gamma * (a · attn) + x ----------------------
// R5 structure, BM=32. grid (128, BB) = 2048 blocks, 5/CU co-resident.
// A-panel (32x256) staged once in LDS (16.6KB); B-frags from global (L2-hot);
// epilogue: shfl-transpose -> float4 x-load + float4 out-store.
#define ALD 260   // At row stride in shorts (520B: bank starts spread, 0 conflicts in R5)
__global__ __launch_bounds__(256, 5) void k_gemm2(const float* __restrict__ x,
                                                  const unsigned short* __restrict__ attnT,
                                                  const float* __restrict__ gamma,
                                                  float* __restrict__ out) {
    __shared__ unsigned short At[32 * ALD];   // 16.6 KB
    const int n0 = blockIdx.x * 32;
    const int b  = blockIdx.y;
    const int t  = threadIdx.x;
    const int w  = t >> 6, l = t & 63;
    const int lk = (l >> 4) * 8, lm = l & 15;

    const float* Abase = x + ((size_t)b * NN + n0) * CC;

    // ---- stage A-panel (32 rows x 256 ch), fully coalesced ----
    #pragma unroll
    for (int r = 0; r < 8; ++r) {
        int idx = r * 256 + t;            // float4 index in the 32x256 panel
        int row = idx >> 6;
        int col = (idx & 63) * 4;
        floatx4 v = *(const floatx4*)(Abase + (size_t)row * CC + col);
        *(short4v*)&At[row * ALD + col] = cvt4(v);
    }
    __syncthreads();                      // the ONLY barrier

    // ---- barrier-free K-loop: A from LDS, B from global (L2-resident) ----
    const unsigned short* Bb = attnT + (size_t)b * CC * CC;
    floatx4 acc[2][4] = {};
    #pragma unroll
    for (int k0 = 0; k0 < CC; k0 += 32) {
        short8v af[2], bf[4];
        #pragma unroll
        for (int mt = 0; mt < 2; ++mt)
            af[mt] = *(const short8v*)&At[(mt * 16 + lm) * ALD + k0 + lk];
        #pragma unroll
        for (int nt = 0; nt < 4; ++nt)
            bf[nt] = *(const short8v*)(Bb + (size_t)(w * 64 + nt * 16 + lm) * CC + k0 + lk);
        #pragma unroll
        for (int mt = 0; mt < 2; ++mt)
            #pragma unroll
            for (int nt = 0; nt < 4; ++nt)
                acc[mt][nt] = __builtin_amdgcn_mfma_f32_16x16x32_bf16(af[mt], bf[nt], acc[mt][nt], 0, 0, 0);
    }

    // ---- epilogue: 4x4 shfl-xor transpose -> float4 ----
    // pre: lane holds col lm, rows orow..orow+3. post: row orow+(lm&3),
    // cols (lm&12)..+3.  (exchange verified lane-by-lane, unchanged from R5.)
    const float g = gamma[0];
    const int orow = (l >> 4) * 4;
    #pragma unroll
    for (int mt = 0; mt < 2; ++mt)
        #pragma unroll
        for (int nt = 0; nt < 4; ++nt) {
            float v0 = acc[mt][nt][0], v1 = acc[mt][nt][1];
            float v2 = acc[mt][nt][2], v3 = acc[mt][nt][3];
            float tt;
            tt = __shfl_xor((lm & 1) ? v0 : v1, 1, 64); if (lm & 1) v0 = tt; else v1 = tt;
            tt = __shfl_xor((lm & 1) ? v2 : v3, 1, 64); if (lm & 1) v2 = tt; else v3 = tt;
            tt = __shfl_xor((lm & 2) ? v0 : v2, 2, 64); if (lm & 2) v0 = tt; else v2 = tt;
            tt = __shfl_xor((lm & 2) ? v1 : v3, 2, 64); if (lm & 2) v1 = tt; else v3 = tt;
            int nr = n0 + mt * 16 + orow + (lm & 3);
            int jc = w * 64 + nt * 16 + (lm & 12);
            size_t ro = ((size_t)b * NN + nr) * CC + jc;
            floatx4 xv = *(const floatx4*)(x + ro);
            floatx4 ov;
            ov[0] = g * v0 + xv[0]; ov[1] = g * v1 + xv[1];
            ov[2] = g * v2 + xv[2]; ov[3] = g * v3 + xv[3];
            *(floatx4*)(out + ro) = ov;
        }
}

extern "C" void kernel_launch(void* const* d_in, const int* in_sizes, int n_in,
                              void* d_out, int out_size, void* d_ws, size_t ws_size,
                              hipStream_t stream) {
    const float* x     = (const float*)d_in[0];
    const float* gamma = (const float*)d_in[1];
    float* out = (float*)d_out;

    char* ws = (char*)d_ws;
    float*          part  = (float*)ws;                                   // 8*16*256*256*4 = 32 MB
    unsigned short* attnT = (unsigned short*)(ws + (size_t)SPLITK * BB * CC * CC * 4);  // 2 MB

    k_gemm1  <<<dim3(SPLITK, BB, 2),  512, 0, stream>>>(x, part);
    k_softmax<<<dim3(BB * CC / 4),    256, 0, stream>>>(part, attnT);
    k_gemm2  <<<dim3(NN / 32, BB),    256, 0, stream>>>(x, attnT, gamma, out);
}

// Round 8
// 170.235 us; speedup vs baseline: 1.0936x; 1.0591x over previous
//
#include <hip/hip_runtime.h>
#include <hip/hip_bf16.h>

// CAM: per batch b (B=16):  a = x[b] viewed as [N=4096, C=256]
//   aTa  = a^T a            [C, C]
//   attn = softmax(aTa, -1)
//   y    = a · attn         [N, C]
//   out  = gamma * y + x
// Storage: fp32 (values bf16-quantized by harness). Internal: bf16 MFMA, fp32 accum.
//
// R7->R8: R7 (gemm2 BM 64->32) regressed 41->51 despite Occ 28->52%: VGPR
// collapsed to 36 (no load pipelining) and B-reuse halved (2x L2 traffic).
// Lesson: don't trade reuse/registers for occupancy. Fallback executed:
//   * gemm2 = EXACT R5 version (41.2us measured best).
//   * gemm1 (this round's single variable): was 256 blocks = exactly
//     1 block/CU -> lockstep zero-refill phases (same disease as R5-gemm2).
//     Now i-range split in 4 quarters: grid (8,16,4)=512 blocks, 8 waves,
//     SAME full [256c x 64n] LDS panel (staging code identical; panel
//     shared by 4 blocks at wgid-distance 128 = same XCD mod 8; x is fully
//     L3-resident so cross-round re-reads are L3-served). Wave tile 32x64,
//     acc[2][4], launch_bounds(512,4) -> 2 blocks/CU, 2 residency rounds:
//     co-resident block's MFMA covers the other's stage/barrier stall.
// NOTE gamma==0 => harness verifies only the x-passthrough; y-path
// correctness rests on hand-verified MFMA/swizzle layouts (unchanged).

#define BB 16
#define NN 4096   // H*W
#define CC 256
#define SPLITK 8
#define KCHUNK (NN / SPLITK)   // 512

typedef __attribute__((ext_vector_type(4))) short short4v;
typedef __attribute__((ext_vector_type(8))) short short8v;
typedef __attribute__((ext_vector_type(4))) float floatx4;

__device__ __forceinline__ unsigned short f2bf(float f) {
    unsigned int u = __float_as_uint(f);
    u += 0x7fffu + ((u >> 16) & 1u);   // RNE (exact for already-bf16-grid values)
    return (unsigned short)(u >> 16);
}
__device__ __forceinline__ short4v cvt4(floatx4 v) {
    short4v r;
    r[0] = (short)f2bf(v[0]); r[1] = (short)f2bf(v[1]);
    r[2] = (short)f2bf(v[2]); r[3] = (short)f2bf(v[3]);
    return r;
}

// ---------------- K1: part[split][b] = partial a^T a (fused transpose) ----
// grid (SPLITK, BB, 4) = 512 blocks, 512 threads (8 waves), 2 blocks/CU.
// Block: rows [q*64, q*64+64) x all 256 cols, k-range of 512 n.
// Staging identical to R2 (full [256c][64n] panel, XOR-swizzled):
// wave w writes short8v at logical chunk 8w, slot s holds n=(s>>3)+8*(s&7);
// XOR key (c>>2)&7 cancels between write and read per-row => effective
// k-permutation row-independent and identical for A/B fragments.
__global__ __launch_bounds__(512, 4) void k_gemm1(const float* __restrict__ x,
                                                  float* __restrict__ part) {
    __shared__ unsigned short P[256 * 72];   // [c][64 slots + pad], 36.9 KB
    const int split = blockIdx.x;
    const int b     = blockIdx.y;
    const int quart = blockIdx.z;
    const int t  = threadIdx.x;
    const int w  = t >> 6, l = t & 63;
    const int lk = (l >> 4) * 8;
    const int lm = l & 15;
    const int i0 = quart * 64;
    const int wr = (w >> 2) * 32;            // wave tile 32 x 64
    const int wc = (w & 3) * 64;
    const unsigned swz = (unsigned)(l & 7) << 3;   // == ((c>>2)&7)<<3 for c=4l+j

    const float* xb = x + ((size_t)b * NN + (size_t)split * KCHUNK) * CC + 4 * l;

    floatx4 pf[8];
    #pragma unroll
    for (int p = 0; p < 8; ++p)
        pf[p] = *(const floatx4*)(xb + (size_t)(w + 8 * p) * CC);   // n = w + 8p

    floatx4 acc[2][4] = {};

    for (int k0 = 0; k0 < KCHUNK; k0 += 64) {
        // bf16 convert + in-register 8x4 -> 4x8 transpose
        short4v s[8];
        #pragma unroll
        for (int p = 0; p < 8; ++p) s[p] = cvt4(pf[p]);
        #pragma unroll
        for (int j = 0; j < 4; ++j) {
            short8v o;
            #pragma unroll
            for (int e = 0; e < 8; ++e) o[e] = s[e][j];   // n = w + 8e
            const unsigned c = (unsigned)(4 * l + j);
            *(short8v*)&P[c * 72 + (((unsigned)(8 * w)) ^ swz)] = o;
        }
        __syncthreads();
        // prefetch next 64-n chunk
        if (k0 + 64 < KCHUNK) {
            const float* xn = xb + (size_t)(k0 + 64) * CC;
            #pragma unroll
            for (int p = 0; p < 8; ++p)
                pf[p] = *(const floatx4*)(xn + (size_t)(w + 8 * p) * CC);
        }
        #pragma unroll
        for (int ks = 0; ks < 64; ks += 32) {
            short8v af[2], bf[4];
            #pragma unroll
            for (int mt = 0; mt < 2; ++mt) {
                const unsigned row = (unsigned)(i0 + wr + mt * 16 + lm);
                af[mt] = *(const short8v*)&P[row * 72 + (((unsigned)(ks + lk)) ^ (((row >> 2) & 7u) << 3))];
            }
            #pragma unroll
            for (int nt = 0; nt < 4; ++nt) {
                const unsigned row = (unsigned)(wc + nt * 16 + lm);
                bf[nt] = *(const short8v*)&P[row * 72 + (((unsigned)(ks + lk)) ^ (((row >> 2) & 7u) << 3))];
            }
            #pragma unroll
            for (int mt = 0; mt < 2; ++mt)
                #pragma unroll
                for (int nt = 0; nt < 4; ++nt)
                    acc[mt][nt] = __builtin_amdgcn_mfma_f32_16x16x32_bf16(af[mt], bf[nt], acc[mt][nt], 0, 0, 0);
        }
        __syncthreads();
    }
    const int orow = (l >> 4) * 4;    // C/D: row=(lane>>4)*4+r, col=lane&15
    float* pout = part + (size_t)(split * BB + b) * CC * CC;
    #pragma unroll
    for (int mt = 0; mt < 2; ++mt)
        #pragma unroll
        for (int nt = 0; nt < 4; ++nt)
            #pragma unroll
            for (int r = 0; r < 4; ++r) {
                int i = i0 + wr + mt * 16 + orow + r;
                int j = wc + nt * 16 + lm;
                pout[(size_t)i * CC + j] = acc[mt][nt][r];
            }
}

// ---------------- K2: attn_T[b][j][i] = softmax over summed partials ----
__global__ __launch_bounds__(256) void k_softmax(const float* __restrict__ part,
                                                 unsigned short* __restrict__ attnT) {
    const int w = threadIdx.x >> 6;
    const int l = threadIdx.x & 63;
    const int row = blockIdx.x * 4 + w;   // 0..B*C-1
    const int b = row >> 8;
    const int i = row & 255;
    float v0 = 0.f, v1 = 0.f, v2 = 0.f, v3 = 0.f;
    #pragma unroll
    for (int s = 0; s < SPLITK; ++s) {
        const float* p = part + ((size_t)(s * BB + b) * CC + i) * CC;
        v0 += p[l]; v1 += p[l + 64]; v2 += p[l + 128]; v3 += p[l + 192];
    }
    float m = fmaxf(fmaxf(v0, v1), fmaxf(v2, v3));
    for (int off = 32; off >= 1; off >>= 1) m = fmaxf(m, __shfl_xor(m, off, 64));
    v0 = __expf(v0 - m); v1 = __expf(v1 - m); v2 = __expf(v2 - m); v3 = __expf(v3 - m);
    float s = v0 + v1 + v2 + v3;
    for (int off = 32; off >= 1; off >>= 1) s += __shfl_xor(s, off, 64);
    float rs = 1.0f / s;
    unsigned short* o = attnT + (size_t)b * CC * CC + i;   // attnT[b][j][i]
    o[(size_t)(l +   0) * CC] = f2bf(v0 * rs);
    o[(size_t)(l +  64) * CC] = f2bf(v1 * rs);
    o[(size_t)(l + 128) * CC] = f2bf(v2 * rs);
    o[(size_t)(l + 192) * CC] = f2bf(v3 * rs);
}

// ---------------- K3: out = gamma * (a · attn) + x ----------------------
// EXACT R5 version (measured 41.2us — best). Barrier-free k-loop;
// A-panel (64x256) staged once; B direct from L2-hot global; shfl-transpose
// float4 epilogue. grid (64, BB) = 1024 blocks.
#define ALD 260   // At row stride in shorts
__global__ __launch_bounds__(256, 4) void k_gemm2(const float* __restrict__ x,
                                                  const unsigned short* __restrict__ attnT,
                                                  const float* __restrict__ gamma,
                                                  float* __restrict__ out) {
    __shared__ unsigned short At[64 * ALD];   // 33.3 KB
    const int n0 = blockIdx.x * 64;
    const int b  = blockIdx.y;
    const int t  = threadIdx.x;
    const int w  = t >> 6, l = t & 63;
    const int lk = (l >> 4) * 8, lm = l & 15;

    const float* Abase = x + ((size_t)b * NN + n0) * CC;

    // ---- stage full A-panel (64 rows x 256 ch), fully coalesced ----
    #pragma unroll
    for (int r = 0; r < 16; ++r) {
        int idx = r * 256 + t;            // float4 index in the 64x256 panel
        int row = idx >> 6;
        int col = (idx & 63) * 4;
        floatx4 v = *(const floatx4*)(Abase + (size_t)row * CC + col);
        *(short4v*)&At[row * ALD + col] = cvt4(v);
    }
    __syncthreads();                      // the ONLY barrier

    // ---- barrier-free K-loop: A from LDS, B from global (L2-resident) ----
    const unsigned short* Bb = attnT + (size_t)b * CC * CC;
    floatx4 acc[4][4] = {};
    #pragma unroll
    for (int k0 = 0; k0 < CC; k0 += 32) {
        short8v af[4], bf[4];
        #pragma unroll
        for (int mt = 0; mt < 4; ++mt)
            af[mt] = *(const short8v*)&At[(mt * 16 + lm) * ALD + k0 + lk];
        #pragma unroll
        for (int nt = 0; nt < 4; ++nt)
            bf[nt] = *(const short8v*)(Bb + (size_t)(w * 64 + nt * 16 + lm) * CC + k0 + lk);
        #pragma unroll
        for (int mt = 0; mt < 4; ++mt)
            #pragma unroll
            for (int nt = 0; nt < 4; ++nt)
                acc[mt][nt] = __builtin_amdgcn_mfma_f32_16x16x32_bf16(af[mt], bf[nt], acc[mt][nt], 0, 0, 0);
    }

    // ---- epilogue: 4x4 shfl-xor transpose -> float4 ----
    const float g = gamma[0];
    const int orow = (l >> 4) * 4;
    #pragma unroll
    for (int mt = 0; mt < 4; ++mt)
        #pragma unroll
        for (int nt = 0; nt < 4; ++nt) {
            float v0 = acc[mt][nt][0], v1 = acc[mt][nt][1];
            float v2 = acc[mt][nt][2], v3 = acc[mt][nt][3];
            float tt;
            tt = __shfl_xor((lm & 1) ? v0 : v1, 1, 64); if (lm & 1) v0 = tt; else v1 = tt;
            tt = __shfl_xor((lm & 1) ? v2 : v3, 1, 64); if (lm & 1) v2 = tt; else v3 = tt;
            tt = __shfl_xor((lm & 2) ? v0 : v2, 2, 64); if (lm & 2) v0 = tt; else v2 = tt;
            tt = __shfl_xor((lm & 2) ? v1 : v3, 2, 64); if (lm & 2) v1 = tt; else v3 = tt;
            int nr = n0 + mt * 16 + orow + (lm & 3);
            int jc = w * 64 + nt * 16 + (lm & 12);
            size_t ro = ((size_t)b * NN + nr) * CC + jc;
            floatx4 xv = *(const floatx4*)(x + ro);
            floatx4 ov;
            ov[0] = g * v0 + xv[0]; ov[1] = g * v1 + xv[1];
            ov[2] = g * v2 + xv[2]; ov[3] = g * v3 + xv[3];
            *(floatx4*)(out + ro) = ov;
        }
}

extern "C" void kernel_launch(void* const* d_in, const int* in_sizes, int n_in,
                              void* d_out, int out_size, void* d_ws, size_t ws_size,
                              hipStream_t stream) {
    const float* x     = (const float*)d_in[0];
    const float* gamma = (const float*)d_in[1];
    float* out = (float*)d_out;

    char* ws = (char*)d_ws;
    float*          part  = (float*)ws;                                   // 8*16*256*256*4 = 32 MB
    unsigned short* attnT = (unsigned short*)(ws + (size_t)SPLITK * BB * CC * CC * 4);  // 2 MB

    k_gemm1  <<<dim3(SPLITK, BB, 4),  512, 0, stream>>>(x, part);
    k_softmax<<<dim3(BB * CC / 4),    256, 0, stream>>>(part, attnT);
    k_gemm2  <<<dim3(NN / 64, BB),    256, 0, stream>>>(x, attnT, gamma, out);
}

// Round 9
// 159.651 us; speedup vs baseline: 1.1661x; 1.0663x over previous
//
#include <hip/hip_runtime.h>
#include <hip/hip_bf16.h>

// CAM: per batch b (B=16):  a = x[b] viewed as [N=4096, C=256]
//   aTa  = a^T a            [C, C]
//   attn = softmax(aTa, -1)
//   y    = a · attn         [N, C]
//   out  = gamma * y + x
// Storage: fp32 (values bf16-quantized by harness). Internal: bf16 MFMA, fp32 accum.
//
// R8->R9: R8 confirmed (both GEMMs now): shrinking wave tiles trades away
// reuse-per-staged-byte for occupancy that isn't the constraint. g1 back to
// R2 shape (grid (8,16,2), 8 waves, acc[4][4], full 256x64 panel) with ONE
// structural change: LDS DOUBLE-BUFFER, single __syncthreads per K-step,
// loop order {issue loads k+1 -> MFMA k -> cvt+write buf^1 -> sync}.
// R2 had 2 syncs/step and issued the prefetch BETWEEN them, so the
// vmcnt(0) drain in the 2nd __syncthreads killed the prefetch before use:
// 8 chip-synchronous full-latency stalls. Now loads are consumed BEFORE
// the barrier -> the drain is costless by construction (no raw-asm
// barriers needed — R4 showed those defeat the scheduler).
// g2 = R5-exact (measured 41-42us anchor). softmax unchanged.
// Swizzle (gamma==0 blinds harness to g1 errors; correct by proof, as R2):
// wave w writes short8v at chunk 8w, slot s holds n=(s>>3)+8*(s&7); XOR key
// (c>>2)&7 cancels write->read per-row => same k-permutation for A and B.

#define BB 16
#define NN 4096   // H*W
#define CC 256
#define SPLITK 8
#define KCHUNK (NN / SPLITK)   // 512

typedef __attribute__((ext_vector_type(4))) short short4v;
typedef __attribute__((ext_vector_type(8))) short short8v;
typedef __attribute__((ext_vector_type(4))) float floatx4;

__device__ __forceinline__ unsigned short f2bf(float f) {
    unsigned int u = __float_as_uint(f);
    u += 0x7fffu + ((u >> 16) & 1u);   // RNE (exact for already-bf16-grid values)
    return (unsigned short)(u >> 16);
}
__device__ __forceinline__ short4v cvt4(floatx4 v) {
    short4v r;
    r[0] = (short)f2bf(v[0]); r[1] = (short)f2bf(v[1]);
    r[2] = (short)f2bf(v[2]); r[3] = (short)f2bf(v[3]);
    return r;
}

// ---------------- K1: part[split][b] = partial a^T a (fused transpose) ----
// grid (SPLITK, BB, 2) = 256 blocks, 512 threads (8 waves).
// Double-buffered panel, ONE sync per K-step.
__global__ __launch_bounds__(512, 2) void k_gemm1(const float* __restrict__ x,
                                                  float* __restrict__ part) {
    __shared__ unsigned short P[2][256 * 72];   // 2 x 36.9 KB
    const int split = blockIdx.x;
    const int b     = blockIdx.y;
    const int half  = blockIdx.z;
    const int t  = threadIdx.x;
    const int w  = t >> 6, l = t & 63;
    const int lk = (l >> 4) * 8;
    const int lm = l & 15;
    const int i0 = half * 128;
    const int wr = (w >> 2) * 64;            // wave tile 64 x 64
    const int wc = (w & 3) * 64;
    const unsigned swz = (unsigned)(l & 7) << 3;   // == ((c>>2)&7)<<3 for c=4l+j

    const float* xb = x + ((size_t)b * NN + (size_t)split * KCHUNK) * CC + 4 * l;

    floatx4 acc[4][4] = {};
    floatx4 pf[8];

    auto LOAD = [&](int k0) {
        const float* xn = xb + (size_t)k0 * CC;
        #pragma unroll
        for (int p = 0; p < 8; ++p)
            pf[p] = *(const floatx4*)(xn + (size_t)(w + 8 * p) * CC);   // n = k0 + w + 8p
    };
    auto CVTWRITE = [&](unsigned short* Pd) {
        short4v s[8];
        #pragma unroll
        for (int p = 0; p < 8; ++p) s[p] = cvt4(pf[p]);
        #pragma unroll
        for (int j = 0; j < 4; ++j) {
            short8v o;
            #pragma unroll
            for (int e = 0; e < 8; ++e) o[e] = s[e][j];   // n = w + 8e
            const unsigned c = (unsigned)(4 * l + j);
            *(short8v*)&Pd[c * 72 + (((unsigned)(8 * w)) ^ swz)] = o;
        }
    };
    auto MFMASTEP = [&](const unsigned short* Ps) {
        #pragma unroll
        for (int ks = 0; ks < 64; ks += 32) {
            short8v af[4], bf[4];
            #pragma unroll
            for (int mt = 0; mt < 4; ++mt) {
                const unsigned row = (unsigned)(i0 + wr + mt * 16 + lm);
                af[mt] = *(const short8v*)&Ps[row * 72 + (((unsigned)(ks + lk)) ^ (((row >> 2) & 7u) << 3))];
            }
            #pragma unroll
            for (int nt = 0; nt < 4; ++nt) {
                const unsigned row = (unsigned)(wc + nt * 16 + lm);
                bf[nt] = *(const short8v*)&Ps[row * 72 + (((unsigned)(ks + lk)) ^ (((row >> 2) & 7u) << 3))];
            }
            #pragma unroll
            for (int mt = 0; mt < 4; ++mt)
                #pragma unroll
                for (int nt = 0; nt < 4; ++nt)
                    acc[mt][nt] = __builtin_amdgcn_mfma_f32_16x16x32_bf16(af[mt], bf[nt], acc[mt][nt], 0, 0, 0);
        }
    };

    // prologue: chunk 0 into buf 0
    LOAD(0);
    CVTWRITE(P[0]);
    __syncthreads();

    #pragma unroll
    for (int s8 = 0; s8 < 8; ++s8) {
        if (s8 < 7) LOAD(s8 * 64 + 64);     // issue next chunk (in flight under MFMA)
        MFMASTEP(P[s8 & 1]);                // compute current buffer
        if (s8 < 7) CVTWRITE(P[(s8 & 1) ^ 1]);  // consume loads, fill other buffer
        __syncthreads();                    // single sync: drain is costless (loads consumed)
    }

    const int orow = (l >> 4) * 4;    // C/D: row=(lane>>4)*4+r, col=lane&15
    float* pout = part + (size_t)(split * BB + b) * CC * CC;
    #pragma unroll
    for (int mt = 0; mt < 4; ++mt)
        #pragma unroll
        for (int nt = 0; nt < 4; ++nt)
            #pragma unroll
            for (int r = 0; r < 4; ++r) {
                int i = i0 + wr + mt * 16 + orow + r;
                int j = wc + nt * 16 + lm;
                pout[(size_t)i * CC + j] = acc[mt][nt][r];
            }
}

// ---------------- K2: attn_T[b][j][i] = softmax over summed partials ----
__global__ __launch_bounds__(256) void k_softmax(const float* __restrict__ part,
                                                 unsigned short* __restrict__ attnT) {
    const int w = threadIdx.x >> 6;
    const int l = threadIdx.x & 63;
    const int row = blockIdx.x * 4 + w;   // 0..B*C-1
    const int b = row >> 8;
    const int i = row & 255;
    float v0 = 0.f, v1 = 0.f, v2 = 0.f, v3 = 0.f;
    #pragma unroll
    for (int s = 0; s < SPLITK; ++s) {
        const float* p = part + ((size_t)(s * BB + b) * CC + i) * CC;
        v0 += p[l]; v1 += p[l + 64]; v2 += p[l + 128]; v3 += p[l + 192];
    }
    float m = fmaxf(fmaxf(v0, v1), fmaxf(v2, v3));
    for (int off = 32; off >= 1; off >>= 1) m = fmaxf(m, __shfl_xor(m, off, 64));
    v0 = __expf(v0 - m); v1 = __expf(v1 - m); v2 = __expf(v2 - m); v3 = __expf(v3 - m);
    float s = v0 + v1 + v2 + v3;
    for (int off = 32; off >= 1; off >>= 1) s += __shfl_xor(s, off, 64);
    float rs = 1.0f / s;
    unsigned short* o = attnT + (size_t)b * CC * CC + i;   // attnT[b][j][i]
    o[(size_t)(l +   0) * CC] = f2bf(v0 * rs);
    o[(size_t)(l +  64) * CC] = f2bf(v1 * rs);
    o[(size_t)(l + 128) * CC] = f2bf(v2 * rs);
    o[(size_t)(l + 192) * CC] = f2bf(v3 * rs);
}

// ---------------- K3: out = gamma * (a · attn) + x ----------------------
// EXACT R5 version (measured 41-42us anchor). Barrier-free k-loop;
// A-panel (64x256) staged once; B direct from L2-hot global; shfl-transpose
// float4 epilogue. grid (64, BB) = 1024 blocks.
#define ALD 260   // At row stride in shorts
__global__ __launch_bounds__(256, 4) void k_gemm2(const float* __restrict__ x,
                                                  const unsigned short* __restrict__ attnT,
                                                  const float* __restrict__ gamma,
                                                  float* __restrict__ out) {
    __shared__ unsigned short At[64 * ALD];   // 33.3 KB
    const int n0 = blockIdx.x * 64;
    const int b  = blockIdx.y;
    const int t  = threadIdx.x;
    const int w  = t >> 6, l = t & 63;
    const int lk = (l >> 4) * 8, lm = l & 15;

    const float* Abase = x + ((size_t)b * NN + n0) * CC;

    // ---- stage full A-panel (64 rows x 256 ch), fully coalesced ----
    #pragma unroll
    for (int r = 0; r < 16; ++r) {
        int idx = r * 256 + t;            // float4 index in the 64x256 panel
        int row = idx >> 6;
        int col = (idx & 63) * 4;
        floatx4 v = *(const floatx4*)(Abase + (size_t)row * CC + col);
        *(short4v*)&At[row * ALD + col] = cvt4(v);
    }
    __syncthreads();                      // the ONLY barrier

    // ---- barrier-free K-loop: A from LDS, B from global (L2-resident) ----
    const unsigned short* Bb = attnT + (size_t)b * CC * CC;
    floatx4 acc[4][4] = {};
    #pragma unroll
    for (int k0 = 0; k0 < CC; k0 += 32) {
        short8v af[4], bf[4];
        #pragma unroll
        for (int mt = 0; mt < 4; ++mt)
            af[mt] = *(const short8v*)&At[(mt * 16 + lm) * ALD + k0 + lk];
        #pragma unroll
        for (int nt = 0; nt < 4; ++nt)
            bf[nt] = *(const short8v*)(Bb + (size_t)(w * 64 + nt * 16 + lm) * CC + k0 + lk);
        #pragma unroll
        for (int mt = 0; mt < 4; ++mt)
            #pragma unroll
            for (int nt = 0; nt < 4; ++nt)
                acc[mt][nt] = __builtin_amdgcn_mfma_f32_16x16x32_bf16(af[mt], bf[nt], acc[mt][nt], 0, 0, 0);
    }

    // ---- epilogue: 4x4 shfl-xor transpose -> float4 ----
    const float g = gamma[0];
    const int orow = (l >> 4) * 4;
    #pragma unroll
    for (int mt = 0; mt < 4; ++mt)
        #pragma unroll
        for (int nt = 0; nt < 4; ++nt) {
            float v0 = acc[mt][nt][0], v1 = acc[mt][nt][1];
            float v2 = acc[mt][nt][2], v3 = acc[mt][nt][3];
            float tt;
            tt = __shfl_xor((lm & 1) ? v0 : v1, 1, 64); if (lm & 1) v0 = tt; else v1 = tt;
            tt = __shfl_xor((lm & 1) ? v2 : v3, 1, 64); if (lm & 1) v2 = tt; else v3 = tt;
            tt = __shfl_xor((lm & 2) ? v0 : v2, 2, 64); if (lm & 2) v0 = tt; else v2 = tt;
            tt = __shfl_xor((lm & 2) ? v1 : v3, 2, 64); if (lm & 2) v1 = tt; else v3 = tt;
            int nr = n0 + mt * 16 + orow + (lm & 3);
            int jc = w * 64 + nt * 16 + (lm & 12);
            size_t ro = ((size_t)b * NN + nr) * CC + jc;
            floatx4 xv = *(const floatx4*)(x + ro);
            floatx4 ov;
            ov[0] = g * v0 + xv[0]; ov[1] = g * v1 + xv[1];
            ov[2] = g * v2 + xv[2]; ov[3] = g * v3 + xv[3];
            *(floatx4*)(out + ro) = ov;
        }
}

extern "C" void kernel_launch(void* const* d_in, const int* in_sizes, int n_in,
                              void* d_out, int out_size, void* d_ws, size_t ws_size,
                              hipStream_t stream) {
    const float* x     = (const float*)d_in[0];
    const float* gamma = (const float*)d_in[1];
    float* out = (float*)d_out;

    char* ws = (char*)d_ws;
    float*          part  = (float*)ws;                                   // 8*16*256*256*4 = 32 MB
    unsigned short* attnT = (unsigned short*)(ws + (size_t)SPLITK * BB * CC * CC * 4);  // 2 MB

    k_gemm1  <<<dim3(SPLITK, BB, 2),  512, 0, stream>>>(x, part);
    k_softmax<<<dim3(BB * CC / 4),    256, 0, stream>>>(part, attnT);
    k_gemm2  <<<dim3(NN / 64, BB),    256, 0, stream>>>(x, attnT, gamma, out);
}